// Round 1
// baseline (496.408 us; speedup 1.0000x reference)
//
#include <hip/hip_runtime.h>
#include <hip/hip_bf16.h>

// Problem constants
#define B_   2
#define C_   64
#define D_   32
#define H_   96
#define W_   96
#define QK_  32
#define TW_  16
#define HW_  (H_*W_)          // 9216
#define DHW_ (D_*H_*W_)       // 294912
#define TDIM_ 256

// ws layout: floats [0,1024) PB[q][d]=bq+tb+pos, [1024,2048) KB2[q][d]=bk+tb+pos
// uints  [2048,3072) wqp (32q x 32 c-pairs), [3072,4096) wkp, [4096,6144) wvp (64 x 32)
#define WS_PB   0
#define WS_KB2  1024
#define WS_WQP  2048
#define WS_WKP  3072
#define WS_WVP  4096

typedef __attribute__((ext_vector_type(8))) short short8;
typedef __attribute__((ext_vector_type(4))) float f32x4;

__device__ __forceinline__ float dot2bf(uint a, uint b, float c) {
    float d;
    asm("v_dot2_f32_bf16 %0, %1, %2, %3" : "=v"(d) : "v"(a), "v"(b), "v"(c));
    return d;
}

__device__ __forceinline__ uint packbf2(float lo, float hi) {
    uint a = (uint)__bfloat16_as_ushort(__float2bfloat16(lo));
    uint b = (uint)__bfloat16_as_ushort(__float2bfloat16(hi));
    return a | (b << 16);
}

__global__ void prep_kernel(const float* __restrict__ te,
                            const float* __restrict__ wt,
                            const float* __restrict__ bt,
                            const float* __restrict__ bq,
                            const float* __restrict__ bk,
                            const float* __restrict__ wq,
                            const float* __restrict__ wk,
                            const float* __restrict__ wv,
                            const float* __restrict__ pos,
                            float* __restrict__ ws) {
    __shared__ float tm[TDIM_];
    __shared__ float qtb[QK_], ktb[QK_];
    const int t = threadIdx.x;
    float s = 0.f;
    #pragma unroll
    for (int tok = 0; tok < 32; ++tok) s += te[tok*TDIM_ + t];
    tm[t] = s * (1.0f/32.0f);
    __syncthreads();
    if (t < QK_) {
        float acc = bt[t];
        for (int c = 0; c < TDIM_; ++c) acc += wt[t*TDIM_ + c] * tm[c];
        qtb[t] = bq[t] + acc;
        ktb[t] = bk[t] + acc;
    }
    __syncthreads();
    // PB / KB2 tables (1024 each): i = q*32 + d
    for (int i = t; i < 1024; i += TDIM_) {
        int q = i >> 5, d = i & 31;
        ws[WS_PB  + i] = qtb[q] + pos[q*32 + d];
        ws[WS_KB2 + i] = ktb[q] + pos[q*32 + d];
    }
    uint* wsu = reinterpret_cast<uint*>(ws);
    for (int i = t; i < 1024; i += TDIM_) {  // wq: 32 q x 32 pairs
        int q = i >> 5, cp = i & 31;
        wsu[WS_WQP + i] = packbf2(wq[q*64 + 2*cp], wq[q*64 + 2*cp + 1]);
    }
    for (int i = t; i < 1024; i += TDIM_) {
        int q = i >> 5, cp = i & 31;
        wsu[WS_WKP + i] = packbf2(wk[q*64 + 2*cp], wk[q*64 + 2*cp + 1]);
    }
    for (int i = t; i < 2048; i += TDIM_) {  // wv: 64 c x 32 pairs
        int c = i >> 5, cp = i & 31;
        wsu[WS_WVP + i] = packbf2(wv[c*64 + 2*cp], wv[c*64 + 2*cp + 1]);
    }
}

// LDS (uints), 96 KiB total -> 1 block/CU (8 waves):
//  xs: 64 c x 256 dwords  (per c: 16 w x 16 e-pair dwords, XOR-swizzled)  = 65536 B
//      -> reused after phase 3 as O1T: 512 rows (d*16+w) x 32 dwords (64 c bf16 pairs)
//  kb: 32 e x 16 w x 16 q-pair dwords (XOR-swizzled)                      = 32768 B
__global__ __launch_bounds__(512, 2)
void attn_main(const float* __restrict__ x,
               const float* __restrict__ bv,
               const float* __restrict__ gm,
               const float* __restrict__ ws,
               float* __restrict__ out) {
    __shared__ uint xs_u[64*256];
    __shared__ uint kb_u[32*256];

    const float* PB  = ws + WS_PB;
    const float* KB2 = ws + WS_KB2;
    const uint*  wsu = reinterpret_cast<const uint*>(ws);
    const uint*  wqp = wsu + WS_WQP;
    const uint*  wkp = wsu + WS_WKP;
    const uint*  wvp = wsu + WS_WVP;

    const int tid = threadIdx.x;
    const int d   = tid >> 4;   // 0..31 depth slice owned
    const int w   = tid & 15;   // 0..15 column within tile

    // Block decode: bx = G*16 + s*8 + r. Partners (s=0,1) are wtile pairs that
    // share 128B output lines and share XCD (bx % 8 == r), adjacent in dispatch.
    const int bx  = blockIdx.x;
    const int r   = bx & 7;
    const int sP  = (bx >> 3) & 1;
    const int G   = bx >> 4;            // 0..71
    const int b   = G / 36;
    const int rem = G % 36;
    const int hh  = rem / 3;
    const int wp  = rem % 3;
    const int h   = hh*8 + r;
    const int wtile = wp*2 + sP;        // 0..5

    const int base = b*(C_*DHW_) + d*HW_ + h*W_ + wtile*TW_ + w;
    const int swx  = (w >> 1) & 3;

    // ---- Phase 0: load own x column; pack bf16 pairs (regs) + scatter to xs ----
    uint xp[32];
    {
        // half-index within a c-row of xs (ushort view), from (w,d) swizzle
        const int slot0 = ((d >> 3) ^ swx) & 3;
        const int hbase = ((w*16 + (slot0 << 2) + ((d >> 1) & 3)) << 1) | (d & 1);
        ushort* xs_h = reinterpret_cast<ushort*>(xs_u);
        #pragma unroll
        for (int cp = 0; cp < 32; ++cp) {
            float v0 = x[base + (2*cp)*DHW_];
            float v1 = x[base + (2*cp+1)*DHW_];
            uint p0 = packbf2(v0, v1);
            xp[cp] = p0;
            xs_h[(2*cp)*512 + hbase]   = (ushort)(p0 & 0xffffu);
            xs_h[(2*cp+1)*512 + hbase] = (ushort)(p0 >> 16);
        }
    }

    // ---- Phase 1: Q (regs, packed) and K (LDS, packed), dot2 over c-pairs ----
    uint Qp[16], kp[16];
    #pragma unroll 2
    for (int qh = 0; qh < 16; ++qh) {
        const int q0 = 2*qh, q1 = 2*qh + 1;
        float aQ0 = PB[q0*32 + d],  aQ1 = PB[q1*32 + d];
        float aK0 = KB2[q0*32 + d], aK1 = KB2[q1*32 + d];
        const uint* wq0 = wqp + q0*32; const uint* wq1 = wqp + q1*32;
        const uint* wk0 = wkp + q0*32; const uint* wk1 = wkp + q1*32;
        #pragma unroll
        for (int cp = 0; cp < 32; ++cp) {
            uint xv = xp[cp];
            aQ0 = dot2bf(wq0[cp], xv, aQ0);
            aQ1 = dot2bf(wq1[cp], xv, aQ1);
            aK0 = dot2bf(wk0[cp], xv, aK0);
            aK1 = dot2bf(wk1[cp], xv, aK1);
        }
        Qp[qh] = packbf2(aQ0, aQ1);
        kp[qh] = packbf2(aK0, aK1);
    }
    // write K row (e=d, w): 4x b128, swizzled slots.  kb layout [e][w][16]
    {
        uint* kw = kb_u + d*256 + w*16;
        const int swk = swx ^ ((d >> 1) & 3);
        #pragma unroll
        for (int g = 0; g < 4; ++g) {
            uint4 v = make_uint4(kp[4*g+0], kp[4*g+1], kp[4*g+2], kp[4*g+3]);
            *reinterpret_cast<uint4*>(kw + (((g ^ swk) & 3) << 2)) = v;
        }
    }
    __syncthreads();

    // ---- Phase 2: S[e] = sum_q Q[q,d] K[q,e] via dot2 over q-pairs ----
    float S[D_];
    #pragma unroll 2
    for (int e = 0; e < D_; ++e) {
        const uint* kr = kb_u + e*256 + w*16;
        const int swk = swx ^ ((e >> 1) & 3);
        float acc = 0.f;
        #pragma unroll
        for (int g = 0; g < 4; ++g) {
            uint4 kv = *reinterpret_cast<const uint4*>(kr + (((g ^ swk) & 3) << 2));
            acc = dot2bf(Qp[4*g+0], kv.x, acc);
            acc = dot2bf(Qp[4*g+1], kv.y, acc);
            acc = dot2bf(Qp[4*g+2], kv.z, acc);
            acc = dot2bf(Qp[4*g+3], kv.w, acc);
        }
        S[e] = acc;
    }

    // ---- softmax over e ----
    const float rsc = 0.17677669529663687f;  // 1/sqrt(32)
    float m = -1e30f;
    #pragma unroll
    for (int e = 0; e < D_; ++e) { S[e] *= rsc; m = fmaxf(m, S[e]); }
    float sum = 0.f;
    #pragma unroll
    for (int e = 0; e < D_; ++e) { float p = __expf(S[e] - m); S[e] = p; sum += p; }
    const float rs = 1.0f / sum;
    uint ap[16];
    #pragma unroll
    for (int ep = 0; ep < 16; ++ep) ap[ep] = packbf2(S[2*ep]*rs, S[2*ep+1]*rs);

    // ---- Phase 3: A[c] = sum_e attn[e] x[c,e]; pack pairs along c ----
    uint Ap[32];
    #pragma unroll 2
    for (int ch = 0; ch < 32; ++ch) {
        float a0 = 0.f, a1 = 0.f;
        const uint* xr0 = xs_u + (2*ch)*256 + w*16;
        const uint* xr1 = xr0 + 256;
        #pragma unroll
        for (int g = 0; g < 4; ++g) {
            const int off = (((g ^ swx) & 3) << 2);
            uint4 u0 = *reinterpret_cast<const uint4*>(xr0 + off);
            uint4 u1 = *reinterpret_cast<const uint4*>(xr1 + off);
            a0 = dot2bf(ap[4*g+0], u0.x, a0);
            a0 = dot2bf(ap[4*g+1], u0.y, a0);
            a0 = dot2bf(ap[4*g+2], u0.z, a0);
            a0 = dot2bf(ap[4*g+3], u0.w, a0);
            a1 = dot2bf(ap[4*g+0], u1.x, a1);
            a1 = dot2bf(ap[4*g+1], u1.y, a1);
            a1 = dot2bf(ap[4*g+2], u1.z, a1);
            a1 = dot2bf(ap[4*g+3], u1.w, a1);
        }
        Ap[ch] = packbf2(a0, a1);
    }

    // ---- Phase 4: O1T dump (xs region reused) then out = wv @ O1 via MFMA ----
    __syncthreads();   // all xs reads done; safe to overwrite with O1T
    {
        // row = d*16 + w: 32 dwords (64 c bf16), 16B slots XOR-swizzled by (w^d)&7
        uint* orow = xs_u + (d*16 + w)*32;
        const int key = (w ^ d) & 7;
        #pragma unroll
        for (int j = 0; j < 8; ++j) {
            uint4 v = make_uint4(Ap[4*j+0], Ap[4*j+1], Ap[4*j+2], Ap[4*j+3]);
            *reinterpret_cast<uint4*>(orow + (((j ^ key) & 7) << 2)) = v;
        }
    }
    __syncthreads();

    // Wave wid handles d = 4*wid + nt (nt 0..3), all 16 w.
    // MFMA 16x16x32 bf16: A[m][k]: m=lane&15, k=8*(lane>>4)+i ; B[k][n]: n=lane&15
    // D[m][n]: n=lane&15, m=4*(lane>>4)+r (m89-verified)
    const int lane = tid & 63;
    const int lg   = lane >> 4;      // k-group / row-group
    const int ln   = lane & 15;      // n-col (= w) / m-row (= c2 low)
    const int wid  = tid >> 6;       // 0..7

    f32x4 acc[4][4];                 // [mt][nt]
    #pragma unroll
    for (int mt = 0; mt < 4; ++mt) {
        const float4 bvv = *reinterpret_cast<const float4*>(bv + 16*mt + 4*lg);
        #pragma unroll
        for (int nt = 0; nt < 4; ++nt) {
            acc[mt][nt][0] = bvv.x; acc[mt][nt][1] = bvv.y;
            acc[mt][nt][2] = bvv.z; acc[mt][nt][3] = bvv.w;
        }
    }
    #pragma unroll
    for (int kt = 0; kt < 2; ++kt) {
        short8 bf[4];
        #pragma unroll
        for (int nt = 0; nt < 4; ++nt) {
            const int dcol = 4*wid + nt;
            const int row  = dcol*16 + ln;                  // O1T row (d,w=ln)
            const int slot = ((4*kt + lg) ^ (ln ^ dcol)) & 7;
            const uint4 raw = *reinterpret_cast<const uint4*>(xs_u + row*32 + (slot << 2));
            bf[nt] = __builtin_bit_cast(short8, raw);
        }
        #pragma unroll
        for (int mt = 0; mt < 4; ++mt) {
            const uint4 araw = *reinterpret_cast<const uint4*>(wvp + (16*mt + ln)*32 + 16*kt + 4*lg);
            const short8 af = __builtin_bit_cast(short8, araw);
            #pragma unroll
            for (int nt = 0; nt < 4; ++nt)
                acc[mt][nt] = __builtin_amdgcn_mfma_f32_16x16x32_bf16(af, bf[nt], acc[mt][nt], 0, 0, 0);
        }
    }

    // ---- stores: out = g*acc + (1-g)*x ; x re-read (L3-resident) for exact residual
    const float gv = 1.0f / (1.0f + __expf(-gm[0]));
    const float gi = 1.0f - gv;
    const int cb0 = b*(C_*DHW_) + h*W_ + wtile*TW_ + ln;
    #pragma unroll
    for (int nt = 0; nt < 4; ++nt) {
        const int dcol = 4*wid + nt;
        const int cb = cb0 + dcol*HW_;
        #pragma unroll
        for (int mt = 0; mt < 4; ++mt) {
            #pragma unroll
            for (int rr = 0; rr < 4; ++rr) {
                const int c2 = 16*mt + 4*lg + rr;
                const int a  = cb + c2*DHW_;
                out[a] = gv*acc[mt][nt][rr] + gi*x[a];
            }
        }
    }
}

extern "C" void kernel_launch(void* const* d_in, const int* in_sizes, int n_in,
                              void* d_out, int out_size, void* d_ws, size_t ws_size,
                              hipStream_t stream) {
    const float* x     = (const float*)d_in[0];
    const float* te    = (const float*)d_in[1];
    const float* wq    = (const float*)d_in[2];
    const float* bq    = (const float*)d_in[3];
    const float* wk    = (const float*)d_in[4];
    const float* bk    = (const float*)d_in[5];
    const float* wv    = (const float*)d_in[6];
    const float* bv    = (const float*)d_in[7];
    const float* wt    = (const float*)d_in[8];
    const float* bt    = (const float*)d_in[9];
    const float* pos   = (const float*)d_in[10];
    const float* gamma = (const float*)d_in[11];
    float* out = (float*)d_out;
    float* ws  = (float*)d_ws;

    prep_kernel<<<1, 256, 0, stream>>>(te, wt, bt, bq, bk, wq, wk, wv, pos, ws);

    const int nblk = B_ * H_ * (W_/TW_);   // 1152 = 72 groups * 16
    attn_main<<<nblk, 512, 0, stream>>>(x, bv, gamma, ws, out);
}